// Round 7
// baseline (201.602 us; speedup 1.0000x reference)
//
#include <hip/hip_runtime.h>
#include <stdint.h>
#include <stddef.h>

typedef _Float16 f16;
typedef _Float16 f16x8 __attribute__((ext_vector_type(8)));
typedef _Float16 f16x4 __attribute__((ext_vector_type(4)));
typedef float f32x4 __attribute__((ext_vector_type(4)));

__device__ __forceinline__ void gload16(const void* g, void* l) {
    auto gp = (const __attribute__((address_space(1))) uint32_t*)(uintptr_t)g;
    auto lp = (__attribute__((address_space(3))) uint32_t*)(uintptr_t)l;
    __builtin_amdgcn_global_load_lds(gp, lp, 16, 0, 0);
}

__device__ __forceinline__ f16x4 cvt4(f32x4 v) {
    return f16x4{ (f16)v[0], (f16)v[1], (f16)v[2], (f16)v[3] };
}

// ---------------- prep: f32 -> f16 conversions --------------------------------
__global__ __launch_bounds__(256) void prep_k(const float* __restrict__ x,
                                              const float* __restrict__ wqkv,
                                              const float* __restrict__ wout,
                                              f16* __restrict__ xb,
                                              f16* __restrict__ wqb,
                                              f16* __restrict__ wob) {
    int tid = blockIdx.x * blockDim.x + threadIdx.x;
    int stride = gridDim.x * blockDim.x;
    for (int i = tid; i < 4194304; i += stride) {
        float4 v = ((const float4*)x)[i];
        *(f16x4*)(xb + (size_t)i * 4) = f16x4{ (f16)v.x, (f16)v.y, (f16)v.z, (f16)v.w };
    }
    for (int i = tid; i < 196608; i += stride) {
        float4 v = ((const float4*)wqkv)[i];
        *(f16x4*)(wqb + (size_t)i * 4) = f16x4{ (f16)v.x, (f16)v.y, (f16)v.z, (f16)v.w };
    }
    for (int i = tid; i < 65536; i += stride) {
        float4 v = ((const float4*)wout)[i];
        *(f16x4*)(wob + (size_t)i * 4) = f16x4{ (f16)v.x, (f16)v.y, (f16)v.z, (f16)v.w };
    }
}

// ---------------- 256x256 tile, BK=64, 8 waves, per-wave 128x64 ---------------
// C[m][n] = sum_k A[m][k]*B[n][k], K=512, row stride 512 f16.
// Geometry makes MFMA the binding port: per CU per K-tile MFMA=2480 cyc >=
// LDS reads 2250 + writes 512. Schedule per tile: STAGE(next) -> RD(cur) ->
// 64-MFMA cluster (reads drain under MFMA issue, stage drains under cluster)
// -> vmcnt(0) -> barrier.  acc[8][4]=128 AGPR; frags 96 VGPR + 12 offsets
// fits the 128 arch-VGPR half at 2 waves/SIMD (r2-verified budget).

#define STAGE(NB) do {                                                          \
    gload16(At + soff,          &ldsA[NB][(  0 + wid*8)*64]);                   \
    gload16(At + soff + 65536,  &ldsA[NB][( 64 + wid*8)*64]);                   \
    gload16(At + soff + 131072, &ldsA[NB][(128 + wid*8)*64]);                   \
    gload16(At + soff + 196608, &ldsA[NB][(192 + wid*8)*64]);                   \
    gload16(Bt + soff,          &ldsB[NB][(  0 + wid*8)*64]);                   \
    gload16(Bt + soff + 65536,  &ldsB[NB][( 64 + wid*8)*64]);                   \
    gload16(Bt + soff + 131072, &ldsB[NB][(128 + wid*8)*64]);                   \
    gload16(Bt + soff + 196608, &ldsB[NB][(192 + wid*8)*64]);                   \
    At += 128; Bt += 128;                                                       \
} while (0)

#define RD(BUF) do {                                                            \
    _Pragma("unroll") for (int ni = 0; ni < 4; ++ni)                            \
    _Pragma("unroll") for (int kk = 0; kk < 2; ++kk)                            \
        bF[ni][kk] = *(const f16x8*)(&ldsB[BUF][0] + boff[ni] + kk * 32);       \
    _Pragma("unroll") for (int mi = 0; mi < 8; ++mi)                            \
    _Pragma("unroll") for (int kk = 0; kk < 2; ++kk)                            \
        aF[mi][kk] = *(const f16x8*)(&ldsA[BUF][0] + aoff[mi] + kk * 32);       \
} while (0)

#define MM do {                                                                 \
    __builtin_amdgcn_s_setprio(1);                                              \
    _Pragma("unroll") for (int mi = 0; mi < 8; ++mi)                            \
    _Pragma("unroll") for (int ni = 0; ni < 4; ++ni)                            \
    _Pragma("unroll") for (int kk = 0; kk < 2; ++kk) {                          \
        if constexpr (SWP)                                                      \
            acc[mi][ni] = __builtin_amdgcn_mfma_f32_16x16x32_f16(               \
                bF[ni][kk], aF[mi][kk], acc[mi][ni], 0, 0, 0);                  \
        else                                                                    \
            acc[mi][ni] = __builtin_amdgcn_mfma_f32_16x16x32_f16(               \
                aF[mi][kk], bF[ni][kk], acc[mi][ni], 0, 0, 0);                  \
    }                                                                           \
    __builtin_amdgcn_s_setprio(0);                                              \
} while (0)

#define W0  asm volatile("s_waitcnt vmcnt(0)" ::: "memory")
#define BAR __builtin_amdgcn_s_barrier()

#define TILE(CB, NB, STG, FINAL) do {                                           \
    if (STG) STAGE(NB);                                                         \
    RD(CB);                                                                     \
    MM;                                                                         \
    if (!FINAL) { W0; BAR; }                                                    \
} while (0)

// MODE 0 + QK:  qkv Q/K part (normal mfma, permuted A rows) -> Q/K [bh][c][lh]
// MODE 0 + SWP: qkv V part   (swapped)                      -> V   [bh][lh][d]
// MODE 1: S = Q K^T * 0.125 per bh (swapped, f16 out)
// MODE 2: Y = P V per bh (normal, f16 out to y[token][c])
// MODE 3: out = y w_out^T + b_out (swapped, f32 out)
template <int MODE, bool SWP, bool QK>
__global__ __launch_bounds__(512, 2) void g11_k(const f16* __restrict__ A0,
                                                const f16* __restrict__ B0,
                                                void* __restrict__ C0,
                                                void* __restrict__ C1,
                                                const float* __restrict__ bias) {
    __shared__ f16 ldsA[2][16384];   // 2 x 256x64, 64 KiB
    __shared__ f16 ldsB[2][16384];   // 2 x 256x64, 64 KiB

    const int tid = threadIdx.x;
    const int lane = tid & 63;
    const int wid = tid >> 6;
    const int wr = wid >> 2;   // 0..1  (M strip of 128)
    const int wc = wid & 3;    // 0..3  (N strip of 64)

    const int bid = blockIdx.x;
    int tm, tn, bh = 0;
    if constexpr (MODE == 0 && QK) {
        int swz = (bid & 7) * 64 + (bid >> 3);        // 512 blocks
        tm = (swz >> 2) * 256; tn = (swz & 3) * 256;
    } else if constexpr (MODE == 0) {
        int swz = (bid & 7) * 32 + (bid >> 3);        // 256 blocks
        tm = (swz >> 1) * 256; tn = (swz & 1) * 256;
    } else if constexpr (MODE == 1 || MODE == 2) {
        int swz = (bid & 7) * 32 + (bid >> 3);        // 256 blocks
        bh = swz >> 2; tm = ((swz >> 1) & 1) * 256; tn = (swz & 1) * 256;
    } else {
        int swz = (bid & 7) * 32 + (bid >> 3);        // 256 blocks
        tm = (swz >> 1) * 256; tn = (swz & 1) * 256;
    }

    const size_t bhoff = (MODE == 1 || MODE == 2) ? (size_t)bh * 262144 : 0;
    const char* At = (const char*)(A0 + bhoff + (size_t)tm * 512);
    const char* Bt = (const char*)(B0 + bhoff + (size_t)tn * 512);

    // staging: row p = line*64 + wid*8 + (lane>>3); chunk = (lane&7) ^ s2(p),
    // s2(p) = (p&3)^((p>>3)&3) = ((lane>>3)&3)^(wid&3) for every staged chunk.
    const int soff = wid * 8192 + (lane >> 3) * 1024 +
                     (((lane & 7) ^ ((lane >> 3) & 3) ^ (wid & 3)) * 16);

    // fragment LDS offsets (f16 units): off = r*64 + ((lane>>4)^s2(r))*8; kk -> +32
    int aoff[8], boff[4];
#pragma unroll
    for (int mi = 0; mi < 8; ++mi) {
        int r;
        if constexpr (QK) {
            r = wr * 128 + (lane & 15) * 8 + mi;       // perm rows: h=mi
        } else {
            r = wr * 128 + mi * 16 + (lane & 15);
        }
        int s2 = (r & 3) ^ ((r >> 3) & 3);
        aoff[mi] = r * 64 + (((lane >> 4) ^ s2)) * 8;
    }
#pragma unroll
    for (int ni = 0; ni < 4; ++ni) {
        int r = wc * 64 + ni * 16 + (lane & 15);
        int s2 = (r & 3) ^ ((r >> 3) & 3);
        boff[ni] = r * 64 + (((lane >> 4) ^ s2)) * 8;
    }

    f32x4 acc[8][4] = {};
    f16x8 aF[8][2], bF[4][2];

    // prologue: stage tile0 -> buf0, drain
    STAGE(0);
    W0; BAR;

    // 8 K-tiles
#pragma unroll 1
    for (int i = 0; i < 3; ++i) {
        TILE(0, 1, true, false);
        TILE(1, 0, true, false);
    }
    TILE(0, 1, true, false);    // t6 (stages tile7 -> buf1)
    TILE(1, 1, false, true);    // t7

    // ---------------- epilogues ----------------
    if constexpr (MODE == 0 && QK) {
        const int b = tm >> 12;
        const int lt = (tm & 4095) >> 3;
        f16* dst = (f16*)(tn < 512 ? C0 : C1);
        const int cb = (tn & 511) + wc * 64;
        const int lh0 = lt + wr * 16 + (lane >> 4) * 4;
#pragma unroll
        for (int mi = 0; mi < 8; ++mi) {
            int h = mi;
#pragma unroll
            for (int ni = 0; ni < 4; ++ni) {
                int c = cb + ni * 16 + (lane & 15);
                *(f16x4*)(dst + ((size_t)((b * 8 + h) * 512 + c)) * 512 + lh0) =
                    cvt4(acc[mi][ni]);
            }
        }
    } else if constexpr (MODE == 0) {      // V, swapped
        f16* dst = (f16*)C0;
#pragma unroll
        for (int mi = 0; mi < 8; ++mi) {
            int t = tm + wr * 128 + mi * 16 + (lane & 15);
            int b = t >> 12, l = t & 4095;
            int h = l & 7, lh = l >> 3;
#pragma unroll
            for (int ni = 0; ni < 4; ++ni) {
                int d0 = tn + wc * 64 + ni * 16 + (lane >> 4) * 4;
                *(f16x4*)(dst + ((size_t)((b * 8 + h) * 512 + lh)) * 512 + d0) =
                    cvt4(acc[mi][ni]);
            }
        }
    } else if constexpr (MODE == 1) {
        f16* S = (f16*)C0 + (size_t)bh * 262144;
#pragma unroll
        for (int mi = 0; mi < 8; ++mi) {
            int cm = tm + wr * 128 + mi * 16 + (lane & 15);
#pragma unroll
            for (int ni = 0; ni < 4; ++ni) {
                int d0 = tn + wc * 64 + ni * 16 + (lane >> 4) * 4;
                *(f16x4*)(S + (size_t)cm * 512 + d0) = cvt4(acc[mi][ni] * 0.125f);
            }
        }
    } else if constexpr (MODE == 2) {
        f16* yb = (f16*)C0;
        const int b = bh >> 3, h = bh & 7;
#pragma unroll
        for (int mi = 0; mi < 8; ++mi) {
            int c0 = tm + wr * 128 + mi * 16 + (lane >> 4) * 4;
#pragma unroll
            for (int ni = 0; ni < 4; ++ni) {
                int l = tn + wc * 64 + ni * 16 + (lane & 15);
                size_t tok = (size_t)b * 4096 + (size_t)l * 8 + h;
                *(f16x4*)(yb + tok * 512 + c0) = cvt4(acc[mi][ni]);
            }
        }
    } else {
        float* O = (float*)C0;
#pragma unroll
        for (int mi = 0; mi < 8; ++mi) {
            int m = tm + wr * 128 + mi * 16 + (lane & 15);
#pragma unroll
            for (int ni = 0; ni < 4; ++ni) {
                int n0 = tn + wc * 64 + ni * 16 + (lane >> 4) * 4;
                float4 bv = *(const float4*)(bias + n0);
                f32x4 v = acc[mi][ni];
                v[0] += bv.x; v[1] += bv.y; v[2] += bv.z; v[3] += bv.w;
                *(f32x4*)(O + (size_t)m * 512 + n0) = v;
            }
        }
    }
}

// ---------------- softmax over 512-wide rows (wave per row, f16 in/out) -------
__global__ __launch_bounds__(256) void softmax_k(const f16* __restrict__ S,
                                                 f16* __restrict__ P) {
    int row = blockIdx.x * 4 + (threadIdx.x >> 6);
    int lane = threadIdx.x & 63;
    f16x8 v = *(const f16x8*)(S + (size_t)row * 512 + lane * 8);
    float f[8];
#pragma unroll
    for (int i = 0; i < 8; ++i) f[i] = (float)v[i];
    float m = f[0];
#pragma unroll
    for (int i = 1; i < 8; ++i) m = fmaxf(m, f[i]);
#pragma unroll
    for (int off = 1; off < 64; off <<= 1) m = fmaxf(m, __shfl_xor(m, off, 64));
    float s = 0.f, e[8];
#pragma unroll
    for (int i = 0; i < 8; ++i) { e[i] = __expf(f[i] - m); s += e[i]; }
#pragma unroll
    for (int off = 1; off < 64; off <<= 1) s += __shfl_xor(s, off, 64);
    float inv = 1.0f / s;
    f16x8 pk;
#pragma unroll
    for (int i = 0; i < 8; ++i) pk[i] = (f16)(e[i] * inv);
    *(f16x8*)(P + (size_t)row * 512 + lane * 8) = pk;
}

// ---------------- launch ------------------------------------------------------
extern "C" void kernel_launch(void* const* d_in, const int* in_sizes, int n_in,
                              void* d_out, int out_size, void* d_ws, size_t ws_size,
                              hipStream_t stream) {
    const float* x = (const float*)d_in[0];
    const float* wqkv = (const float*)d_in[1];
    const float* wout = (const float*)d_in[2];
    const float* bout = (const float*)d_in[3];
    float* out = (float*)d_out;
    char* ws = (char*)d_ws;
    const size_t MBs = 1u << 20;

    f16* xb  = (f16*)(ws + 0);            // 32MB
    f16* wqb = (f16*)(ws + 32 * MBs);     // 1.5MB
    f16* wob = (f16*)(ws + 34 * MBs);     // 0.5MB
    f16* Qb  = (f16*)(ws + 35 * MBs);     // 32MB
    f16* Kb  = (f16*)(ws + 67 * MBs);     // 32MB
    f16* Vb  = (f16*)(ws + 99 * MBs);     // 32MB
    f16* Sb  = (f16*)(ws + 131 * MBs);    // 32MB (total 163MB)
    f16* Pb  = xb;                        // alias: xb dead after V GEMM
    f16* yb  = Qb;                        // alias: Q dead after S GEMM

    prep_k<<<1024, 256, 0, stream>>>(x, wqkv, wout, xb, wqb, wob);
    g11_k<0, false, true><<<512, 512, 0, stream>>>(xb, wqb, Qb, Kb, nullptr);
    g11_k<0, true, false><<<256, 512, 0, stream>>>(xb, wqb + (size_t)1024 * 512, Vb, nullptr, nullptr);
    g11_k<1, true, false><<<256, 512, 0, stream>>>(Qb, Kb, Sb, nullptr, nullptr);
    softmax_k<<<8192, 256, 0, stream>>>(Sb, Pb);
    g11_k<2, false, false><<<256, 512, 0, stream>>>(Pb, Vb, yb, nullptr, nullptr);
    g11_k<3, true, false><<<256, 512, 0, stream>>>(yb, wob, out, nullptr, bout);
}

// Round 8
// 190.383 us; speedup vs baseline: 1.0589x; 1.0589x over previous
//
#include <hip/hip_runtime.h>
#include <stdint.h>
#include <stddef.h>

typedef _Float16 f16;
typedef _Float16 f16x8 __attribute__((ext_vector_type(8)));
typedef _Float16 f16x4 __attribute__((ext_vector_type(4)));
typedef float f32x4 __attribute__((ext_vector_type(4)));

__device__ __forceinline__ void gload16(const void* g, void* l) {
    auto gp = (const __attribute__((address_space(1))) uint32_t*)(uintptr_t)g;
    auto lp = (__attribute__((address_space(3))) uint32_t*)(uintptr_t)l;
    __builtin_amdgcn_global_load_lds(gp, lp, 16, 0, 0);
}

__device__ __forceinline__ f16x4 cvt4(f32x4 v) {
    return f16x4{ (f16)v[0], (f16)v[1], (f16)v[2], (f16)v[3] };
}

// ---------------- prep: f32 -> f16 conversions --------------------------------
__global__ __launch_bounds__(256) void prep_k(const float* __restrict__ x,
                                              const float* __restrict__ wqkv,
                                              const float* __restrict__ wout,
                                              f16* __restrict__ xb,
                                              f16* __restrict__ wqb,
                                              f16* __restrict__ wob) {
    int tid = blockIdx.x * blockDim.x + threadIdx.x;
    int stride = gridDim.x * blockDim.x;
    for (int i = tid; i < 4194304; i += stride) {
        float4 v = ((const float4*)x)[i];
        *(f16x4*)(xb + (size_t)i * 4) = f16x4{ (f16)v.x, (f16)v.y, (f16)v.z, (f16)v.w };
    }
    for (int i = tid; i < 196608; i += stride) {
        float4 v = ((const float4*)wqkv)[i];
        *(f16x4*)(wqb + (size_t)i * 4) = f16x4{ (f16)v.x, (f16)v.y, (f16)v.z, (f16)v.w };
    }
    for (int i = tid; i < 65536; i += stride) {
        float4 v = ((const float4*)wout)[i];
        *(f16x4*)(wob + (size_t)i * 4) = f16x4{ (f16)v.x, (f16)v.y, (f16)v.z, (f16)v.w };
    }
}

// ---------------- 256x256 tile, BK=64, 8 waves, per-wave 128x64, kk-phased ----
// C[m][n] = sum_k A[m][k]*B[n][k], K=512, row stride 512 f16.
// Per-wave 128x64 output: intensity 43.7 FLOP/LDS-byte -> MFMA is the binding
// port (2480 cyc/CU/tile vs ~2050 LDS).  Register discipline: ONE 12-frag set
// (48 VGPR) rewritten per kk-phase; same-reg WAR keeps liveness flat.
// Per K-tile: RD12(kk0) -> STAGE8(next) -> MM32 -> RD12(kk1) -> MM32 -> W0;BAR.
// kk1 reads drain under kk0's MFMA execution; stage waits a full tile (~2400cyc).

#define STAGE(NB) do {                                                          \
    gload16(At + soff,          &ldsA[NB][(  0 + wid*8)*64]);                   \
    gload16(At + soff + 65536,  &ldsA[NB][( 64 + wid*8)*64]);                   \
    gload16(At + soff + 131072, &ldsA[NB][(128 + wid*8)*64]);                   \
    gload16(At + soff + 196608, &ldsA[NB][(192 + wid*8)*64]);                   \
    gload16(Bt + soff,          &ldsB[NB][(  0 + wid*8)*64]);                   \
    gload16(Bt + soff + 65536,  &ldsB[NB][( 64 + wid*8)*64]);                   \
    gload16(Bt + soff + 131072, &ldsB[NB][(128 + wid*8)*64]);                   \
    gload16(Bt + soff + 196608, &ldsB[NB][(192 + wid*8)*64]);                   \
    At += 128; Bt += 128;                                                       \
} while (0)

#define RD12(KK, BUF) do {                                                      \
    _Pragma("unroll") for (int ni = 0; ni < 4; ++ni)                            \
        bF[ni] = *(const f16x8*)(&ldsB[BUF][0] + boff[ni][KK]);                 \
    _Pragma("unroll") for (int mi = 0; mi < 8; ++mi)                            \
        aF[mi] = *(const f16x8*)(&ldsA[BUF][0] + aoff[mi][KK]);                 \
} while (0)

#define MM32 do {                                                               \
    __builtin_amdgcn_s_setprio(1);                                              \
    _Pragma("unroll") for (int mi = 0; mi < 8; ++mi)                            \
    _Pragma("unroll") for (int ni = 0; ni < 4; ++ni) {                          \
        if constexpr (SWP)                                                      \
            acc[mi][ni] = __builtin_amdgcn_mfma_f32_16x16x32_f16(               \
                bF[ni], aF[mi], acc[mi][ni], 0, 0, 0);                          \
        else                                                                    \
            acc[mi][ni] = __builtin_amdgcn_mfma_f32_16x16x32_f16(               \
                aF[mi], bF[ni], acc[mi][ni], 0, 0, 0);                          \
    }                                                                           \
    __builtin_amdgcn_s_setprio(0);                                              \
} while (0)

#define W0  asm volatile("s_waitcnt vmcnt(0)" ::: "memory")
#define BAR __builtin_amdgcn_s_barrier()

#define TILE(CB, NB, STG, FINAL) do {                                           \
    RD12(0, CB);                                                                \
    if (STG) STAGE(NB);                                                         \
    MM32;                                                                       \
    RD12(1, CB);                                                                \
    MM32;                                                                       \
    if (!FINAL) { W0; BAR; }                                                    \
} while (0)

// MODE 0 + QK:  qkv Q/K part (normal mfma, permuted A rows) -> Q/K [bh][c][lh]
// MODE 0 + SWP: qkv V part   (swapped)                      -> V   [bh][lh][d]
// MODE 1: S = Q K^T * 0.125 per bh (swapped, f16 out)
// MODE 2: Y = P V per bh (normal, f16 out to y[token][c])
// MODE 3: out = y w_out^T + b_out (swapped, f32 out)
template <int MODE, bool SWP, bool QK>
__global__ __launch_bounds__(512) void g12_k(const f16* __restrict__ A0,
                                             const f16* __restrict__ B0,
                                             void* __restrict__ C0,
                                             void* __restrict__ C1,
                                             const float* __restrict__ bias) {
    __shared__ f16 ldsA[2][16384];   // 2 x 256x64, 64 KiB
    __shared__ f16 ldsB[2][16384];   // 2 x 256x64, 64 KiB

    const int tid = threadIdx.x;
    const int lane = tid & 63;
    const int wid = tid >> 6;
    const int wr = wid >> 2;   // 0..1  (M strip of 128)
    const int wc = wid & 3;    // 0..3  (N strip of 64)

    const int bid = blockIdx.x;
    int tm, tn, bh = 0;
    if constexpr (MODE == 0 && QK) {
        int swz = (bid & 7) * 64 + (bid >> 3);        // 512 blocks
        tm = (swz >> 2) * 256; tn = (swz & 3) * 256;
    } else if constexpr (MODE == 0) {
        int swz = (bid & 7) * 32 + (bid >> 3);        // 256 blocks
        tm = (swz >> 1) * 256; tn = (swz & 1) * 256;
    } else if constexpr (MODE == 1 || MODE == 2) {
        int swz = (bid & 7) * 32 + (bid >> 3);        // 256 blocks
        bh = swz >> 2; tm = ((swz >> 1) & 1) * 256; tn = (swz & 1) * 256;
    } else {
        int swz = (bid & 7) * 32 + (bid >> 3);        // 256 blocks
        tm = (swz >> 1) * 256; tn = (swz & 1) * 256;
    }

    const size_t bhoff = (MODE == 1 || MODE == 2) ? (size_t)bh * 262144 : 0;
    const char* At = (const char*)(A0 + bhoff + (size_t)tm * 512);
    const char* Bt = (const char*)(B0 + bhoff + (size_t)tn * 512);

    // staging: row r = line*64 + wid*8 + (lane>>3); s3(r) = (lane>>3) ^ wid;
    // chunk = (lane&7) ^ s3  -> one per-lane byte offset for all 8 loads.
    const int soff = wid * 8192 + (lane >> 3) * 1024 +
                     ((((lane & 7) ^ (lane >> 3) ^ wid) & 7) * 16);

    // fragment LDS offsets (f16 units): off = r*64 + ((c8 ^ s3(r)))*8,
    // c8 = (lane>>4) + kk*4, s3(r) = (r&7)^((r>>3)&7).
    int aoff[8][2], boff[4][2];
#pragma unroll
    for (int mi = 0; mi < 8; ++mi) {
        int r;
        if constexpr (QK) {
            r = wr * 128 + (lane & 15) * 8 + mi;       // perm rows: h=mi
        } else {
            r = wr * 128 + mi * 16 + (lane & 15);
        }
        int s3 = (r & 7) ^ ((r >> 3) & 7);
#pragma unroll
        for (int kk = 0; kk < 2; ++kk)
            aoff[mi][kk] = r * 64 + ((((lane >> 4) + kk * 4) ^ s3)) * 8;
    }
#pragma unroll
    for (int ni = 0; ni < 4; ++ni) {
        int r = wc * 64 + ni * 16 + (lane & 15);
        int s3 = (r & 7) ^ ((r >> 3) & 7);
#pragma unroll
        for (int kk = 0; kk < 2; ++kk)
            boff[ni][kk] = r * 64 + ((((lane >> 4) + kk * 4) ^ s3)) * 8;
    }

    f32x4 acc[8][4] = {};
    f16x8 aF[8], bF[4];

    // prologue: stage tile0 -> buf0, drain
    STAGE(0);
    W0; BAR;

    // 8 K-tiles
#pragma unroll 1
    for (int i = 0; i < 3; ++i) {
        TILE(0, 1, true, false);
        TILE(1, 0, true, false);
    }
    TILE(0, 1, true, false);    // t6 (stages tile7 -> buf1)
    TILE(1, 1, false, true);    // t7

    // ---------------- epilogues ----------------
    if constexpr (MODE == 0 && QK) {
        const int b = tm >> 12;
        const int lt = (tm & 4095) >> 3;
        f16* dst = (f16*)(tn < 512 ? C0 : C1);
        const int cb = (tn & 511) + wc * 64;
        const int lh0 = lt + wr * 16 + (lane >> 4) * 4;
#pragma unroll
        for (int mi = 0; mi < 8; ++mi) {
            int h = mi;
#pragma unroll
            for (int ni = 0; ni < 4; ++ni) {
                int c = cb + ni * 16 + (lane & 15);
                *(f16x4*)(dst + ((size_t)((b * 8 + h) * 512 + c)) * 512 + lh0) =
                    cvt4(acc[mi][ni]);
            }
        }
    } else if constexpr (MODE == 0) {      // V, swapped
        f16* dst = (f16*)C0;
#pragma unroll
        for (int mi = 0; mi < 8; ++mi) {
            int t = tm + wr * 128 + mi * 16 + (lane & 15);
            int b = t >> 12, l = t & 4095;
            int h = l & 7, lh = l >> 3;
#pragma unroll
            for (int ni = 0; ni < 4; ++ni) {
                int d0 = tn + wc * 64 + ni * 16 + (lane >> 4) * 4;
                *(f16x4*)(dst + ((size_t)((b * 8 + h) * 512 + lh)) * 512 + d0) =
                    cvt4(acc[mi][ni]);
            }
        }
    } else if constexpr (MODE == 1) {
        f16* S = (f16*)C0 + (size_t)bh * 262144;
#pragma unroll
        for (int mi = 0; mi < 8; ++mi) {
            int cm = tm + wr * 128 + mi * 16 + (lane & 15);
#pragma unroll
            for (int ni = 0; ni < 4; ++ni) {
                int d0 = tn + wc * 64 + ni * 16 + (lane >> 4) * 4;
                *(f16x4*)(S + (size_t)cm * 512 + d0) = cvt4(acc[mi][ni] * 0.125f);
            }
        }
    } else if constexpr (MODE == 2) {
        f16* yb = (f16*)C0;
        const int b = bh >> 3, h = bh & 7;
#pragma unroll
        for (int mi = 0; mi < 8; ++mi) {
            int c0 = tm + wr * 128 + mi * 16 + (lane >> 4) * 4;
#pragma unroll
            for (int ni = 0; ni < 4; ++ni) {
                int l = tn + wc * 64 + ni * 16 + (lane & 15);
                size_t tok = (size_t)b * 4096 + (size_t)l * 8 + h;
                *(f16x4*)(yb + tok * 512 + c0) = cvt4(acc[mi][ni]);
            }
        }
    } else {
        float* O = (float*)C0;
#pragma unroll
        for (int mi = 0; mi < 8; ++mi) {
            int m = tm + wr * 128 + mi * 16 + (lane & 15);
#pragma unroll
            for (int ni = 0; ni < 4; ++ni) {
                int n0 = tn + wc * 64 + ni * 16 + (lane >> 4) * 4;
                float4 bv = *(const float4*)(bias + n0);
                f32x4 v = acc[mi][ni];
                v[0] += bv.x; v[1] += bv.y; v[2] += bv.z; v[3] += bv.w;
                *(f32x4*)(O + (size_t)m * 512 + n0) = v;
            }
        }
    }
}

// ---------------- softmax over 512-wide rows (wave per row, f16 in/out) -------
__global__ __launch_bounds__(256) void softmax_k(const f16* __restrict__ S,
                                                 f16* __restrict__ P) {
    int row = blockIdx.x * 4 + (threadIdx.x >> 6);
    int lane = threadIdx.x & 63;
    f16x8 v = *(const f16x8*)(S + (size_t)row * 512 + lane * 8);
    float f[8];
#pragma unroll
    for (int i = 0; i < 8; ++i) f[i] = (float)v[i];
    float m = f[0];
#pragma unroll
    for (int i = 1; i < 8; ++i) m = fmaxf(m, f[i]);
#pragma unroll
    for (int off = 1; off < 64; off <<= 1) m = fmaxf(m, __shfl_xor(m, off, 64));
    float s = 0.f, e[8];
#pragma unroll
    for (int i = 0; i < 8; ++i) { e[i] = __expf(f[i] - m); s += e[i]; }
#pragma unroll
    for (int off = 1; off < 64; off <<= 1) s += __shfl_xor(s, off, 64);
    float inv = 1.0f / s;
    f16x8 pk;
#pragma unroll
    for (int i = 0; i < 8; ++i) pk[i] = (f16)(e[i] * inv);
    *(f16x8*)(P + (size_t)row * 512 + lane * 8) = pk;
}

// ---------------- launch ------------------------------------------------------
extern "C" void kernel_launch(void* const* d_in, const int* in_sizes, int n_in,
                              void* d_out, int out_size, void* d_ws, size_t ws_size,
                              hipStream_t stream) {
    const float* x = (const float*)d_in[0];
    const float* wqkv = (const float*)d_in[1];
    const float* wout = (const float*)d_in[2];
    const float* bout = (const float*)d_in[3];
    float* out = (float*)d_out;
    char* ws = (char*)d_ws;
    const size_t MBs = 1u << 20;

    f16* xb  = (f16*)(ws + 0);            // 32MB
    f16* wqb = (f16*)(ws + 32 * MBs);     // 1.5MB
    f16* wob = (f16*)(ws + 34 * MBs);     // 0.5MB
    f16* Qb  = (f16*)(ws + 35 * MBs);     // 32MB
    f16* Kb  = (f16*)(ws + 67 * MBs);     // 32MB
    f16* Vb  = (f16*)(ws + 99 * MBs);     // 32MB
    f16* Sb  = (f16*)(ws + 131 * MBs);    // 32MB (total 163MB)
    f16* Pb  = xb;                        // alias: xb dead after V GEMM
    f16* yb  = Qb;                        // alias: Q dead after S GEMM

    prep_k<<<1024, 256, 0, stream>>>(x, wqkv, wout, xb, wqb, wob);
    g12_k<0, false, true><<<512, 512, 0, stream>>>(xb, wqb, Qb, Kb, nullptr);
    g12_k<0, true, false><<<256, 512, 0, stream>>>(xb, wqb + (size_t)1024 * 512, Vb, nullptr, nullptr);
    g12_k<1, true, false><<<256, 512, 0, stream>>>(Qb, Kb, Sb, nullptr, nullptr);
    softmax_k<<<8192, 256, 0, stream>>>(Sb, Pb);
    g12_k<2, false, false><<<256, 512, 0, stream>>>(Pb, Vb, yb, nullptr, nullptr);
    g12_k<3, true, false><<<256, 512, 0, stream>>>(yb, wob, out, nullptr, bout);
}